// Round 7
// baseline (419.278 us; speedup 1.0000x reference)
//
#include <hip/hip_runtime.h>

typedef unsigned short u16;
typedef unsigned int   u32;
typedef __attribute__((ext_vector_type(8))) short          short8;
typedef __attribute__((ext_vector_type(4))) float          f32x4;
typedef __attribute__((ext_vector_type(8))) unsigned short u16x8;
typedef __attribute__((ext_vector_type(4))) unsigned short u16x4;

#define T_SEQ  2048
#define DMODEL 1024
#define NHEAD  16
#define DHEAD  64
#define HBUF   4194304   // elems in one (B,H,T,DH) buffer = 2*16*2048*64

__device__ __forceinline__ float bf2f(u16 u) {
    u32 i = ((u32)u) << 16; float f; __builtin_memcpy(&f, &i, 4); return f;
}
__device__ __forceinline__ u16 f2bf(float f) {
    u32 x; __builtin_memcpy(&x, &f, 4);
    return (u16)((x + 0x7FFFu + ((x >> 16) & 1u)) >> 16);   // RNE
}

// async global->LDS, 16B per lane; LDS dest = wave-uniform base + lane*16 (m97/m104)
__device__ __forceinline__ void gld16(const u16* g, u16* l) {
    auto gp = reinterpret_cast<const __attribute__((address_space(1))) u32*>(
        reinterpret_cast<uintptr_t>(g));
    auto lp = reinterpret_cast<__attribute__((address_space(3))) u32*>(
        (u32)reinterpret_cast<uintptr_t>(l));
    __builtin_amdgcn_global_load_lds(gp, lp, 16, 0, 0);
}

// counted vmcnt wait (compile-time literal)
template<int N> __device__ __forceinline__ void wait_vmcnt() {
    if constexpr (N == 0)      asm volatile("s_waitcnt vmcnt(0)" ::: "memory");
    else if constexpr (N == 2) asm volatile("s_waitcnt vmcnt(2)" ::: "memory");
    else                       asm volatile("s_waitcnt vmcnt(4)" ::: "memory");
}

// T1: bijective XCD-aware swizzle (nwg % 8 == 0 for all our grids)
__device__ __forceinline__ void xcd_swz(int& bx, int& by) {
    int gx = gridDim.x;
    int nwg = gx * gridDim.y;
    int w = by * gx + bx;
    int L = (w & 7) * (nwg >> 3) + (w >> 3);
    bx = L % gx; by = L / gx;
}

// ---------------- LayerNorm (f32 in -> bf16 out): one block per row of 1024 ----------------
__global__ __launch_bounds__(256) void ln_k(const float* __restrict__ x,
                                            const float* __restrict__ g,
                                            const float* __restrict__ bb,
                                            u16* __restrict__ out)
{
    int row = blockIdx.x, tid = threadIdx.x;
    const float* xr = x + (size_t)row * DMODEL;
    f32x4 v = *(const f32x4*)(xr + tid * 4);
    float s  = v[0] + v[1] + v[2] + v[3];
    float s2 = v[0]*v[0] + v[1]*v[1] + v[2]*v[2] + v[3]*v[3];
    #pragma unroll
    for (int o = 32; o; o >>= 1) { s += __shfl_xor(s, o); s2 += __shfl_xor(s2, o); }
    __shared__ float rs[4], rq[4];
    if ((tid & 63) == 0) { rs[tid >> 6] = s; rq[tid >> 6] = s2; }
    __syncthreads();
    float S  = rs[0] + rs[1] + rs[2] + rs[3];
    float S2 = rq[0] + rq[1] + rq[2] + rq[3];
    float mean = S * (1.f / DMODEL);
    float var  = S2 * (1.f / DMODEL) - mean * mean;
    float rstd = rsqrtf(var + 1e-5f);
    f32x4 gv = *(const f32x4*)(g + tid * 4);
    f32x4 bv = *(const f32x4*)(bb + tid * 4);
    u16x4 o;
    #pragma unroll
    for (int e = 0; e < 4; e++)
        o[e] = f2bf((v[e] - mean) * rstd * gv[e] + bv[e]);
    *(u16x4*)(out + (size_t)row * DMODEL + tid * 4) = o;
}

// -------- 64x64-tile transpose + f32->bf16 convert: out[c][r] = bf16(in[r][c]) --------
__device__ __forceinline__ void tr_body(const float* __restrict__ in,
                                        u16* __restrict__ out, int R, int C,
                                        int bx, int by, int tid)
{
    __shared__ u16 s[64][72];
    int c0 = bx * 64, r0 = by * 64;
    #pragma unroll
    for (int p = 0; p < 2; p++) {
        int r = (tid >> 3) + p * 32, cq = (tid & 7) * 8;
        const float* ip = in + (size_t)(r0 + r) * C + c0 + cq;
        f32x4 a = *(const f32x4*)ip;
        f32x4 b = *(const f32x4*)(ip + 4);
        u16x8 o;
        #pragma unroll
        for (int e = 0; e < 4; e++) { o[e] = f2bf(a[e]); o[4 + e] = f2bf(b[e]); }
        *(u16x8*)(&s[r][cq]) = o;
    }
    __syncthreads();
    int oc = tid >> 2, kq = (tid & 3) * 16;
    u16 tmp[16] __attribute__((aligned(16)));
    #pragma unroll
    for (int e = 0; e < 16; e++) tmp[e] = s[kq + e][oc];
    u16* op = out + (size_t)(c0 + oc) * R + r0 + kq;
    *(u16x8*)op       = *(const u16x8*)(&tmp[0]);
    *(u16x8*)(op + 8) = *(const u16x8*)(&tmp[8]);
}

// ALL weight transposes in one launch. grid (16,16,12)
__global__ __launch_bounds__(256) void trall_k(const float* __restrict__ w0, const float* __restrict__ w1,
                                               const float* __restrict__ w2, const float* __restrict__ w3,
                                               const float* __restrict__ wf1, const float* __restrict__ wf2,
                                               u16* __restrict__ o0, u16* __restrict__ o1,
                                               u16* __restrict__ o2, u16* __restrict__ o3,
                                               u16* __restrict__ of1, u16* __restrict__ of2)
{
    int z = blockIdx.z;
    if (z < 4) {
        const float* in = (z == 0) ? w0 : (z == 1) ? w1 : (z == 2) ? w2 : w3;
        u16* out        = (z == 0) ? o0 : (z == 1) ? o1 : (z == 2) ? o2 : o3;
        tr_body(in, out, 1024, 1024, blockIdx.x, blockIdx.y, threadIdx.x);
    } else if (z < 8) {
        tr_body(wf1, of1, 1024, 4096, blockIdx.x + 16 * (z - 4), blockIdx.y, threadIdx.x);
    } else {
        tr_body(wf2, of2, 4096, 1024, blockIdx.x, blockIdx.y + 16 * (z - 8), threadIdx.x);
    }
}

constexpr int EPI_QKV = 0, EPI_RESF = 1, EPI_GELU = 2, EPI_RES2 = 3;

// ---- fused epilogue element (non-QKV paths) ----
template<int EPI>
__device__ __forceinline__ void epi_elem(
    float v, int m, int n, int N, void* outv,
    const float* b0, const float* resid)
{
    if constexpr (EPI == EPI_RESF) {
        v += b0[n] + resid[(size_t)m * N + n];
        ((float*)outv)[(size_t)m * N + n] = v;   // f32 residual stream
    } else if constexpr (EPI == EPI_GELU) {
        v += b0[n];
        float gl = 0.5f * v * (1.f + erff(v * 0.70710678118654752f));
        ((u16*)outv)[(size_t)m * N + n] = f2bf(gl);
    } else { // EPI_RES2 -> f32 final output
        v += b0[n] + resid[(size_t)m * N + n];
        ((float*)outv)[(size_t)m * N + n] = v;
    }
}

// ======== 128x128-tile GEMM, 512 threads = 8 waves (2M x 4N), BK=32 ========
// Round-4 proven structure (tri-buffer global_load_lds + counted vmcnt + raw
// barrier + plain C++ LDS reads so the compiler keeps fine-grained lgkmcnt
// interleaving of ds_read with MFMA — r6 showed hand LGKM0 drains regress 15%).
// ONE change vs r4: READ-LINEAR LDS layout (r6-verified, conflicts 6.3M -> 0):
// staging source is (row = lane&15, granule = lane>>4) with linear gld16 dests,
// so LDS slot l of each 16-row 1KB block holds (row=l&15, gran=l>>4) — exactly
// the (lm,ko) fragment order. Every compute lane reads base + lane*16B (the
// same lane-linear pattern gld16 writes): zero bank conflicts by construction,
// identical data & global cache-line footprint (same 16x64B lines per instr).
template<int EPI>
__global__ __launch_bounds__(512) void gemm8_k(
    const u16* __restrict__ A, const u16* __restrict__ Bt, void* __restrict__ outv,
    int M, int N, int K, int Kld,
    const float* __restrict__ b0, const float* __restrict__ b1, const float* __restrict__ b2,
    const float* __restrict__ resid,
    const float* __restrict__ cosp, const float* __restrict__ sinp)
{
    (void)M;
    constexpr int TSZ = 128 * 32;            // elems per buffer (8KB)
    __shared__ u16 As[3 * TSZ];              // 24KB tri-buffered
    __shared__ u16 Bs[3 * TSZ];              // 24KB
    int tid = threadIdx.x;
    int bx = blockIdx.x, by = blockIdx.y;
    xcd_swz(bx, by);
    int n0 = bx * 128, m0 = by * 128;
    int wave = tid >> 6, lane = tid & 63, lm = lane & 15, ko = lane >> 4;
    int wm2 = wave >> 2, wn2 = wave & 3;     // wave -> 64-row half x 32-col quarter

    f32x4 acc[4][2];
    #pragma unroll
    for (int i = 0; i < 4; i++)
        #pragma unroll
        for (int j = 0; j < 2; j++) acc[i][j] = (f32x4){0.f, 0.f, 0.f, 0.f};

    // staging: wave w covers rows w*16..+15; lane sources (row=lane&15, gran=lane>>4)
    int sr = lane & 15, sg = lane >> 4;
    const u16* Ag = A  + (size_t)(m0 + wave * 16 + sr) * Kld + sg * 8;
    const u16* Bg = Bt + (size_t)(n0 + wave * 16 + sr) * Kld + sg * 8;
    u16* Al = &As[wave * 512];               // wave-uniform dest (lane*16B implicit)
    u16* Bl = &Bs[wave * 512];

    auto issue = [&](int t, int b) {
        gld16(Ag + t * 32, Al + b * TSZ);
        gld16(Bg + t * 32, Bl + b * TSZ);
    };

    int NT = K >> 5;
    issue(0, 0);
    issue(1, 1);

    int bc = 0, bn = 2;
    for (int kt = 0; kt < NT; kt++) {
        if (kt + 1 < NT) wait_vmcnt<2>();    // retire tile kt's 2 loads, keep kt+1's in flight
        else             wait_vmcnt<0>();
        __builtin_amdgcn_s_barrier();
        __builtin_amdgcn_sched_barrier(0);
        if (kt + 2 < NT) issue(kt + 2, bn);  // refill buffer last read before PREVIOUS barrier

        const u16* Ab = &As[bc * TSZ];
        const u16* Bb = &Bs[bc * TSZ];
        short8 af[4], bf[2];
        #pragma unroll
        for (int i = 0; i < 4; i++)          // row-block rb = wm2*4+i : lane-linear read
            af[i] = *(const short8*)(&Ab[(wm2 * 4 + i) * 512 + lane * 8]);
        #pragma unroll
        for (int j = 0; j < 2; j++)          // row-block rb = wn2*2+j
            bf[j] = *(const short8*)(&Bb[(wn2 * 2 + j) * 512 + lane * 8]);
        __builtin_amdgcn_s_setprio(1);
        #pragma unroll
        for (int i = 0; i < 4; i++)
            #pragma unroll
            for (int j = 0; j < 2; j++)
                acc[i][j] = __builtin_amdgcn_mfma_f32_16x16x32_bf16(af[i], bf[j], acc[i][j], 0, 0, 0);
        __builtin_amdgcn_s_setprio(0);
        bc = (bc == 2) ? 0 : bc + 1;
        bn = (bn == 2) ? 0 : bn + 1;
    }

    // epilogue — C/D layout: col = lane&15, row = (lane>>4)*4 + reg  [m89/m91]
    #pragma unroll
    for (int i = 0; i < 4; i++) {
        #pragma unroll
        for (int j = 0; j < 2; j++) {
            int n = n0 + wn2 * 32 + j * 16 + lm;
            int mb = m0 + wm2 * 64 + i * 16 + ko * 4;   // rows mb..mb+3 (wave-uniform which)
            if constexpr (EPI == EPI_QKV) {
                int which = n >> 10, nn = n & 1023;     // uniform across the wave
                const float* bp = (which == 0) ? b0 : (which == 1 ? b1 : b2);
                float bias = bp[nn];
                int bi = mb >> 11, t2b = mb & 2047;
                int hh = nn >> 6, d = nn & 63;
                u16* outp = (u16*)outv + (size_t)which * HBUF;
                if (which == 2) {
                    // V stored transposed (B,H,DH,T): 4 consecutive t2 -> one 8B store
                    u16x4 o;
                    #pragma unroll
                    for (int r = 0; r < 4; r++) o[r] = f2bf(acc[i][j][r] + bias);
                    *(u16x4*)(&outp[((size_t)((bi * NHEAD + hh) * DHEAD + d)) * T_SEQ + t2b]) = o;
                } else {
                    #pragma unroll
                    for (int r = 0; r < 4; r++) {
                        float v = acc[i][j][r] + bias;
                        float vp = __shfl_xor(v, 1);    // RoPE partner (col^1)
                        int t2 = t2b + r;
                        size_t ci = (size_t)t2 * 32 + (d >> 1);   // broadcast slice (b=0,h=0)
                        float c = cosp[ci], sn2 = sinp[ci];
                        float o = (d & 1) ? (vp * sn2 + v * c) : (v * c - vp * sn2);
                        if (which == 0) o *= 0.18033688f;         // 1/sqrt(DH) * log2(e)
                        outp[((size_t)((bi * NHEAD + hh) * T_SEQ + t2)) * DHEAD + d] = f2bf(o);
                    }
                }
            } else {
                #pragma unroll
                for (int r = 0; r < 4; r++)
                    epi_elem<EPI>(acc[i][j][r], mb + r, n, N, outv, b0, resid);
            }
        }
    }
}

// ---------------- flash attention (MFMA), fixed-max softmax ----------------
__device__ __forceinline__ void attn_step(
    bool diag, int wave, int lm, int ko,
    short8 aq0, short8 aq1,
    const u16 (*sK)[72], const u16 (*sV)[72], u16 (*sPw)[72],
    f32x4* oacc, float* lr)
{
    f32x4 sacc[4];
    #pragma unroll
    for (int j = 0; j < 4; j++) {
        short8 bk0 = *(const short8*)(&sK[j * 16 + lm][ko * 8]);
        short8 bk1 = *(const short8*)(&sK[j * 16 + lm][32 + ko * 8]);
        f32x4 z = (f32x4){0.f, 0.f, 0.f, 0.f};
        z = __builtin_amdgcn_mfma_f32_16x16x32_bf16(aq0, bk0, z, 0, 0, 0);
        z = __builtin_amdgcn_mfma_f32_16x16x32_bf16(aq1, bk1, z, 0, 0, 0);
        sacc[j] = z;
    }
    if (diag) {
        #pragma unroll
        for (int j = 0; j < 4; j++)
            #pragma unroll
            for (int r = 0; r < 4; r++)
                if (j * 16 + lm > wave * 16 + ko * 4 + r) sacc[j][r] = -1e30f;
    }

    u16 pb[4][4];
    #pragma unroll
    for (int j = 0; j < 4; j++)
        #pragma unroll
        for (int r = 0; r < 4; r++) {
            float p = __builtin_amdgcn_exp2f(sacc[j][r]);
            lr[r] += p;
            pb[j][r] = f2bf(p);
        }

    #pragma unroll
    for (int j = 0; j < 4; j++)
        #pragma unroll
        for (int r = 0; r < 4; r++) sPw[ko * 4 + r][j * 16 + lm] = pb[j][r];

    #pragma unroll
    for (int ks = 0; ks < 2; ks++) {
        short8 ap = *(const short8*)(&sPw[lm][ks * 32 + ko * 8]);
        #pragma unroll
        for (int j = 0; j < 4; j++) {
            short8 bv = *(const short8*)(&sV[j * 16 + lm][ks * 32 + ko * 8]);
            oacc[j] = __builtin_amdgcn_mfma_f32_16x16x32_bf16(ap, bv, oacc[j], 0, 0, 0);
        }
    }
}

__global__ __launch_bounds__(256) void fattn_k(const u16* __restrict__ Q,
                                               const u16* __restrict__ K,
                                               const u16* __restrict__ Vt,
                                               u16* __restrict__ out)
{
    __shared__ u16 sQP[4][16][72];
    __shared__ u16 sK[2][64][72];
    __shared__ u16 sV[2][64][72];
    int tid = threadIdx.x;
    int qtA = blockIdx.x;
    int qtB = 31 - qtA;
    int bh = blockIdx.y;
    int wave = tid >> 6, lane = tid & 63, lm = lane & 15, ko = lane >> 4;
    int bi = bh >> 4, hh = bh & 15;

    const u16* Kb = K  + (size_t)bh * T_SEQ * DHEAD;
    const u16* Vb = Vt + (size_t)bh * DHEAD * T_SEQ;
    u16* sQf = &sQP[0][0][0];
    int srow = tid >> 2, scol = (tid & 3) * 16;

    short8 aqA0, aqA1, aqB0, aqB1;
    {
        const u16* QbA = Q + ((size_t)bh * T_SEQ + qtA * 64) * DHEAD + (size_t)srow * DHEAD + scol;
        *(u16x8*)(&sQf[srow * 72 + scol])     = *(const u16x8*)QbA;
        *(u16x8*)(&sQf[srow * 72 + scol + 8]) = *(const u16x8*)(QbA + 8);
        __syncthreads();
        aqA0 = *(const short8*)(&sQf[(wave * 16 + lm) * 72 + ko * 8]);
        aqA1 = *(const short8*)(&sQf[(wave * 16 + lm) * 72 + 32 + ko * 8]);
        __syncthreads();
        const u16* QbB = Q + ((size_t)bh * T_SEQ + qtB * 64) * DHEAD + (size_t)srow * DHEAD + scol;
        *(u16x8*)(&sQf[srow * 72 + scol])     = *(const u16x8*)QbB;
        *(u16x8*)(&sQf[srow * 72 + scol + 8]) = *(const u16x8*)(QbB + 8);
        __syncthreads();
        aqB0 = *(const short8*)(&sQf[(wave * 16 + lm) * 72 + ko * 8]);
        aqB1 = *(const short8*)(&sQf[(wave * 16 + lm) * 72 + 32 + ko * 8]);
    }

    f32x4 oA[4], oB[4];
    float lA[4], lB[4];
    #pragma unroll
    for (int j = 0; j < 4; j++) { oA[j] = (f32x4){0,0,0,0}; oB[j] = (f32x4){0,0,0,0}; }
    #pragma unroll
    for (int r = 0; r < 4; r++) { lA[r] = 0.f; lB[r] = 0.f; }

    int nA = qtA + 1, n = nA + qtB + 1;

    u16x8 pk0, pk1, pv0, pv1;
    {
        const u16* kp = Kb + (size_t)srow * DHEAD + scol;
        pk0 = *(const u16x8*)kp; pk1 = *(const u16x8*)(kp + 8);
        const u16* vp = Vb + (size_t)srow * T_SEQ + scol;
        pv0 = *(const u16x8*)vp; pv1 = *(const u16x8*)(vp + 8);
    }

    for (int i = 0; i < n; i++) {
        bool isA = i < nA;
        int kt = isA ? i : i - nA;
        int buf = i & 1;

        *(u16x8*)(&sK[buf][srow][scol])     = pk0;
        *(u16x8*)(&sK[buf][srow][scol + 8]) = pk1;
        *(u16x8*)(&sV[buf][srow][scol])     = pv0;
        *(u16x8*)(&sV[buf][srow][scol + 8]) = pv1;

        if (i + 1 < n) {
            int kt2 = (i + 1 < nA) ? i + 1 : i + 1 - nA;
            const u16* kp = Kb + ((size_t)(kt2 * 64 + srow)) * DHEAD + scol;
            pk0 = *(const u16x8*)kp; pk1 = *(const u16x8*)(kp + 8);
            const u16* vp = Vb + (size_t)srow * T_SEQ + kt2 * 64 + scol;
            pv0 = *(const u16x8*)vp; pv1 = *(const u16x8*)(vp + 8);
        }

        __syncthreads();

        if (isA)
            attn_step(kt == qtA, wave, lm, ko, aqA0, aqA1, sK[buf], sV[buf], sQP[wave], oA, lA);
        else
            attn_step(kt == qtB, wave, lm, ko, aqB0, aqB1, sK[buf], sV[buf], sQP[wave], oB, lB);
    }

    #pragma unroll
    for (int o = 1; o < 16; o <<= 1)
        #pragma unroll
        for (int r = 0; r < 4; r++) { lA[r] += __shfl_xor(lA[r], o); lB[r] += __shfl_xor(lB[r], o); }
    #pragma unroll
    for (int r = 0; r < 4; r++) { lA[r] = 1.f / lA[r]; lB[r] = 1.f / lB[r]; }
    int qrowA = qtA * 64 + wave * 16, qrowB = qtB * 64 + wave * 16;
    #pragma unroll
    for (int j = 0; j < 4; j++)
        #pragma unroll
        for (int r = 0; r < 4; r++) {
            out[((size_t)(bi * T_SEQ) + qrowA + ko * 4 + r) * DMODEL + hh * DHEAD + j * 16 + lm]
                = f2bf(oA[j][r] * lA[r]);
            out[((size_t)(bi * T_SEQ) + qrowB + ko * 4 + r) * DMODEL + hh * DHEAD + j * 16 + lm]
                = f2bf(oB[j][r] * lB[r]);
        }
}

// ---------------- host launch ----------------
extern "C" void kernel_launch(void* const* d_in, const int* in_sizes, int n_in,
                              void* d_out, int out_size, void* d_ws, size_t ws_size,
                              hipStream_t stream)
{
    (void)in_sizes; (void)n_in; (void)out_size; (void)ws_size;
    const float* x    = (const float*)d_in[0];
    const float* cosp = (const float*)d_in[1];
    const float* sinp = (const float*)d_in[2];
    const float* Wq  = (const float*)d_in[4];
    const float* bq  = (const float*)d_in[5];
    const float* Wk  = (const float*)d_in[6];
    const float* bk  = (const float*)d_in[7];
    const float* Wv  = (const float*)d_in[8];
    const float* bv  = (const float*)d_in[9];
    const float* Wo  = (const float*)d_in[10];
    const float* bo  = (const float*)d_in[11];
    const float* g1  = (const float*)d_in[12];
    const float* b1n = (const float*)d_in[13];
    const float* g2  = (const float*)d_in[14];
    const float* b2n = (const float*)d_in[15];
    const float* W1  = (const float*)d_in[16];
    const float* bf1 = (const float*)d_in[17];
    const float* W2  = (const float*)d_in[18];
    const float* bf2 = (const float*)d_in[19];

    char* ws = (char*)d_ws;
    const size_t MB = 1024 * 1024;
    u16*   qkvT  = (u16*)(ws + 0);        // Wq^T,Wk^T,Wv^T bf16: (3072,1024), 6 MB
    u16*   WoT   = (u16*)(ws + 6 * MB);   // 2 MB
    u16*   W1T   = (u16*)(ws + 8 * MB);   // (4096,1024), 8 MB
    u16*   W2T   = (u16*)(ws + 16 * MB);  // (1024,4096), 8 MB
    u16*   h     = (u16*)(ws + 24 * MB);  // LN output bf16 (reused as h2), 8 MB
    u16*   qkvh  = (u16*)(ws + 32 * MB);  // Q,K in (B,H,T,DH); V in (B,H,DH,T), 3x8 MB
    u16*   attnC = (u16*)(ws + 56 * MB);  // attention out bf16 (B,T,D), 8 MB
    float* x2    = (float*)(ws + 64 * MB);// f32 residual stream, 16 MB
    u16*   ffnh  = (u16*)(ws + 80 * MB);  // bf16 (4096,4096), 32 MB

    trall_k<<<dim3(16, 16, 12), 256, 0, stream>>>(
        Wq, Wk, Wv, Wo, W1, W2,
        qkvT, qkvT + 1 * MB, qkvT + 2 * MB, WoT, W1T, W2T);

    ln_k<<<4096, 256, 0, stream>>>(x, g1, b1n, h);
    gemm8_k<EPI_QKV><<<dim3(24, 32), 512, 0, stream>>>(
        h, qkvT, qkvh, 4096, 3072, 1024, 1024, bq, bk, bv, nullptr, cosp, sinp);
    fattn_k<<<dim3(16, 32), 256, 0, stream>>>(qkvh, qkvh + HBUF, qkvh + 2 * HBUF, attnC);
    gemm8_k<EPI_RESF><<<dim3(8, 32), 512, 0, stream>>>(
        attnC, WoT, x2, 4096, 1024, 1024, 1024, bo, nullptr, nullptr, x, nullptr, nullptr);
    ln_k<<<4096, 256, 0, stream>>>(x2, g2, b2n, h);
    gemm8_k<EPI_GELU><<<dim3(32, 32), 512, 0, stream>>>(
        h, W1T, ffnh, 4096, 4096, 1024, 1024, bf1, nullptr, nullptr, nullptr, nullptr, nullptr);
    gemm8_k<EPI_RES2><<<dim3(8, 32), 512, 0, stream>>>(
        ffnh, W2T, (float*)d_out, 4096, 1024, 4096, 4096, bf2, nullptr, nullptr, x2, nullptr, nullptr);
}

// Round 8
// 373.680 us; speedup vs baseline: 1.1220x; 1.1220x over previous
//
#include <hip/hip_runtime.h>

typedef unsigned short u16;
typedef unsigned int   u32;
typedef __attribute__((ext_vector_type(8))) short          short8;
typedef __attribute__((ext_vector_type(4))) float          f32x4;
typedef __attribute__((ext_vector_type(8))) unsigned short u16x8;
typedef __attribute__((ext_vector_type(4))) unsigned short u16x4;
typedef __attribute__((ext_vector_type(4))) u32            u32x4;

#define T_SEQ  2048
#define DMODEL 1024
#define NHEAD  16
#define DHEAD  64
#define HBUF   4194304   // elems in one (B,H,T,DH) buffer = 2*16*2048*64

__device__ __forceinline__ float bf2f(u16 u) {
    u32 i = ((u32)u) << 16; float f; __builtin_memcpy(&f, &i, 4); return f;
}
__device__ __forceinline__ u16 f2bf(float f) {
    u32 x; __builtin_memcpy(&x, &f, 4);
    return (u16)((x + 0x7FFFu + ((x >> 16) & 1u)) >> 16);   // RNE
}

// async global->LDS, 16B per lane; LDS dest = wave-uniform base + lane*16 (m97/m104)
__device__ __forceinline__ void gld16(const u16* g, u16* l) {
    auto gp = reinterpret_cast<const __attribute__((address_space(1))) u32*>(
        reinterpret_cast<uintptr_t>(g));
    auto lp = reinterpret_cast<__attribute__((address_space(3))) u32*>(
        (u32)reinterpret_cast<uintptr_t>(l));
    __builtin_amdgcn_global_load_lds(gp, lp, 16, 0, 0);
}

// inline-asm ds_read_b128: OPAQUE to alias analysis, so the backend cannot
// insert a conservative `s_waitcnt vmcnt(0)` before it to protect against
// in-flight global_load_lds (the suspected ~900cy/step stall in r0/r1/r4).
// Requires manual lgkmcnt(0) + sched_barrier(0) before use (rule #18).
__device__ __forceinline__ short8 dsr128(u32 addr) {
    u32x4 r;
    asm volatile("ds_read_b128 %0, %1" : "=&v"(r) : "v"(addr));
    return __builtin_bit_cast(short8, r);
}

// counted vmcnt wait (compile-time literal)
template<int N> __device__ __forceinline__ void wait_vmcnt() {
    if constexpr (N == 0)      asm volatile("s_waitcnt vmcnt(0)" ::: "memory");
    else if constexpr (N == 2) asm volatile("s_waitcnt vmcnt(2)" ::: "memory");
    else                       asm volatile("s_waitcnt vmcnt(4)" ::: "memory");
}

// T1: bijective XCD-aware swizzle (nwg % 8 == 0 for all our grids)
__device__ __forceinline__ void xcd_swz(int& bx, int& by) {
    int gx = gridDim.x;
    int nwg = gx * gridDim.y;
    int w = by * gx + bx;
    int L = (w & 7) * (nwg >> 3) + (w >> 3);
    bx = L % gx; by = L / gx;
}

// ---------------- LayerNorm (f32 in -> bf16 out): one block per row of 1024 ----------------
__global__ __launch_bounds__(256) void ln_k(const float* __restrict__ x,
                                            const float* __restrict__ g,
                                            const float* __restrict__ bb,
                                            u16* __restrict__ out)
{
    int row = blockIdx.x, tid = threadIdx.x;
    const float* xr = x + (size_t)row * DMODEL;
    f32x4 v = *(const f32x4*)(xr + tid * 4);
    float s  = v[0] + v[1] + v[2] + v[3];
    float s2 = v[0]*v[0] + v[1]*v[1] + v[2]*v[2] + v[3]*v[3];
    #pragma unroll
    for (int o = 32; o; o >>= 1) { s += __shfl_xor(s, o); s2 += __shfl_xor(s2, o); }
    __shared__ float rs[4], rq[4];
    if ((tid & 63) == 0) { rs[tid >> 6] = s; rq[tid >> 6] = s2; }
    __syncthreads();
    float S  = rs[0] + rs[1] + rs[2] + rs[3];
    float S2 = rq[0] + rq[1] + rq[2] + rq[3];
    float mean = S * (1.f / DMODEL);
    float var  = S2 * (1.f / DMODEL) - mean * mean;
    float rstd = rsqrtf(var + 1e-5f);
    f32x4 gv = *(const f32x4*)(g + tid * 4);
    f32x4 bv = *(const f32x4*)(bb + tid * 4);
    u16x4 o;
    #pragma unroll
    for (int e = 0; e < 4; e++)
        o[e] = f2bf((v[e] - mean) * rstd * gv[e] + bv[e]);
    *(u16x4*)(out + (size_t)row * DMODEL + tid * 4) = o;
}

// -------- 64x64-tile transpose + f32->bf16 convert: out[c][r] = bf16(in[r][c]) --------
__device__ __forceinline__ void tr_body(const float* __restrict__ in,
                                        u16* __restrict__ out, int R, int C,
                                        int bx, int by, int tid)
{
    __shared__ u16 s[64][72];
    int c0 = bx * 64, r0 = by * 64;
    #pragma unroll
    for (int p = 0; p < 2; p++) {
        int r = (tid >> 3) + p * 32, cq = (tid & 7) * 8;
        const float* ip = in + (size_t)(r0 + r) * C + c0 + cq;
        f32x4 a = *(const f32x4*)ip;
        f32x4 b = *(const f32x4*)(ip + 4);
        u16x8 o;
        #pragma unroll
        for (int e = 0; e < 4; e++) { o[e] = f2bf(a[e]); o[4 + e] = f2bf(b[e]); }
        *(u16x8*)(&s[r][cq]) = o;
    }
    __syncthreads();
    int oc = tid >> 2, kq = (tid & 3) * 16;
    u16 tmp[16] __attribute__((aligned(16)));
    #pragma unroll
    for (int e = 0; e < 16; e++) tmp[e] = s[kq + e][oc];
    u16* op = out + (size_t)(c0 + oc) * R + r0 + kq;
    *(u16x8*)op       = *(const u16x8*)(&tmp[0]);
    *(u16x8*)(op + 8) = *(const u16x8*)(&tmp[8]);
}

// ALL weight transposes in one launch. grid (16,16,12)
__global__ __launch_bounds__(256) void trall_k(const float* __restrict__ w0, const float* __restrict__ w1,
                                               const float* __restrict__ w2, const float* __restrict__ w3,
                                               const float* __restrict__ wf1, const float* __restrict__ wf2,
                                               u16* __restrict__ o0, u16* __restrict__ o1,
                                               u16* __restrict__ o2, u16* __restrict__ o3,
                                               u16* __restrict__ of1, u16* __restrict__ of2)
{
    int z = blockIdx.z;
    if (z < 4) {
        const float* in = (z == 0) ? w0 : (z == 1) ? w1 : (z == 2) ? w2 : w3;
        u16* out        = (z == 0) ? o0 : (z == 1) ? o1 : (z == 2) ? o2 : o3;
        tr_body(in, out, 1024, 1024, blockIdx.x, blockIdx.y, threadIdx.x);
    } else if (z < 8) {
        tr_body(wf1, of1, 1024, 4096, blockIdx.x + 16 * (z - 4), blockIdx.y, threadIdx.x);
    } else {
        tr_body(wf2, of2, 4096, 1024, blockIdx.x, blockIdx.y + 16 * (z - 8), threadIdx.x);
    }
}

constexpr int EPI_QKV = 0, EPI_RESF = 1, EPI_GELU = 2, EPI_RES2 = 3;

// ---- fused epilogue element (non-QKV paths) ----
template<int EPI>
__device__ __forceinline__ void epi_elem(
    float v, int m, int n, int N, void* outv,
    const float* b0, const float* resid)
{
    if constexpr (EPI == EPI_RESF) {
        v += b0[n] + resid[(size_t)m * N + n];
        ((float*)outv)[(size_t)m * N + n] = v;   // f32 residual stream
    } else if constexpr (EPI == EPI_GELU) {
        v += b0[n];
        float gl = 0.5f * v * (1.f + erff(v * 0.70710678118654752f));
        ((u16*)outv)[(size_t)m * N + n] = f2bf(gl);
    } else { // EPI_RES2 -> f32 final output
        v += b0[n] + resid[(size_t)m * N + n];
        ((float*)outv)[(size_t)m * N + n] = v;
    }
}

// ======== 128x128-tile GEMM, 512 threads = 8 waves (2M x 4N), BK=32 ========
// EXACT round-4 structure (best verified: 375us total) with ONE isolated change:
// fragment reads use inline-asm ds_read_b128 + a single lgkmcnt(0)+sched_barrier
// before the MFMA cluster. Rationale: plain C++ LDS reads may alias the LDS
// dests of in-flight global_load_lds, so the backend inserts s_waitcnt vmcnt(0)
// before them — draining the JUST-ISSUED kt+2 prefetch and exposing ~900cy HBM
// latency every K-step (consistent with r0==r1 and r4's 1088cy/step vs ~220cy
// of work). asm reads are opaque to alias analysis, so the counted vmcnt<2>
// prefetch pipeline actually holds. Staging pattern/layout/epilogues = r4
// byte-for-byte; K-order unchanged -> bit-identical outputs.
template<int EPI>
__global__ __launch_bounds__(512) void gemm8_k(
    const u16* __restrict__ A, const u16* __restrict__ Bt, void* __restrict__ outv,
    int M, int N, int K, int Kld,
    const float* __restrict__ b0, const float* __restrict__ b1, const float* __restrict__ b2,
    const float* __restrict__ resid,
    const float* __restrict__ cosp, const float* __restrict__ sinp)
{
    (void)M;
    constexpr int TSZ = 128 * 32;            // elems per buffer (8KB)
    __shared__ u16 As[3 * TSZ];              // 24KB tri-buffered
    __shared__ u16 Bs[3 * TSZ];              // 24KB
    int tid = threadIdx.x;
    int bx = blockIdx.x, by = blockIdx.y;
    xcd_swz(bx, by);
    int n0 = bx * 128, m0 = by * 128;
    int wave = tid >> 6, lane = tid & 63, lm = lane & 15, ko = lane >> 4;
    int wm2 = wave >> 2, wn2 = wave & 3;     // wave -> 64-row half x 32-col quarter

    f32x4 acc[4][2];
    #pragma unroll
    for (int i = 0; i < 4; i++)
        #pragma unroll
        for (int j = 0; j < 2; j++) acc[i][j] = (f32x4){0.f, 0.f, 0.f, 0.f};

    // staging: 512 thr x 16B = 8KB per matrix per K-step (1 gld16 each) — r4 pattern
    int srow = tid >> 2;                     // 0..127
    int scol = (tid & 3) * 8;
    const u16* Ag = A  + (size_t)(m0 + srow) * Kld + scol;
    const u16* Bg = Bt + (size_t)(n0 + srow) * Kld + scol;
    u16* Al = &As[wave * 16 * 32];           // wave-uniform base: rows wave*16..+15
    u16* Bl = &Bs[wave * 16 * 32];

    auto issue = [&](int t, int b) {
        gld16(Ag + t * 32, Al + b * TSZ);
        gld16(Bg + t * 32, Bl + b * TSZ);
    };

    int NT = K >> 5;
    issue(0, 0);
    issue(1, 1);

    const u32 Asb = (u32)(uintptr_t)&As[0];
    const u32 Bsb = (u32)(uintptr_t)&Bs[0];

    int bc = 0, bn = 2;
    for (int kt = 0; kt < NT; kt++) {
        if (kt + 1 < NT) wait_vmcnt<2>();    // retire tile kt's 2 loads, keep kt+1's in flight
        else             wait_vmcnt<0>();
        __builtin_amdgcn_s_barrier();
        __builtin_amdgcn_sched_barrier(0);
        if (kt + 2 < NT) issue(kt + 2, bn);  // refill buffer last read before PREVIOUS barrier

        u32 Ab = Asb + (u32)(bc * (TSZ * 2));
        u32 Bb = Bsb + (u32)(bc * (TSZ * 2));
        short8 af[4], bf[2];
        #pragma unroll
        for (int i = 0; i < 4; i++)
            af[i] = dsr128(Ab + (u32)(((wm2 * 64 + i * 16 + lm) * 32 + ko * 8) * 2));
        #pragma unroll
        for (int j = 0; j < 2; j++)
            bf[j] = dsr128(Bb + (u32)(((wn2 * 32 + j * 16 + lm) * 32 + ko * 8) * 2));
        asm volatile("s_waitcnt lgkmcnt(0)" ::: "memory");
        __builtin_amdgcn_sched_barrier(0);   // rule #18: no MFMA hoist above the wait
        __builtin_amdgcn_s_setprio(1);
        #pragma unroll
        for (int i = 0; i < 4; i++)
            #pragma unroll
            for (int j = 0; j < 2; j++)
                acc[i][j] = __builtin_amdgcn_mfma_f32_16x16x32_bf16(af[i], bf[j], acc[i][j], 0, 0, 0);
        __builtin_amdgcn_s_setprio(0);
        bc = (bc == 2) ? 0 : bc + 1;
        bn = (bn == 2) ? 0 : bn + 1;
    }

    // epilogue — C/D layout: col = lane&15, row = (lane>>4)*4 + reg  [m89/m91]
    #pragma unroll
    for (int i = 0; i < 4; i++) {
        #pragma unroll
        for (int j = 0; j < 2; j++) {
            int n = n0 + wn2 * 32 + j * 16 + lm;
            int mb = m0 + wm2 * 64 + i * 16 + ko * 4;   // rows mb..mb+3 (wave-uniform which)
            if constexpr (EPI == EPI_QKV) {
                int which = n >> 10, nn = n & 1023;     // uniform across the wave
                const float* bp = (which == 0) ? b0 : (which == 1 ? b1 : b2);
                float bias = bp[nn];
                int bi = mb >> 11, t2b = mb & 2047;
                int hh = nn >> 6, d = nn & 63;
                u16* outp = (u16*)outv + (size_t)which * HBUF;
                if (which == 2) {
                    // V stored transposed (B,H,DH,T): 4 consecutive t2 -> one 8B store
                    u16x4 o;
                    #pragma unroll
                    for (int r = 0; r < 4; r++) o[r] = f2bf(acc[i][j][r] + bias);
                    *(u16x4*)(&outp[((size_t)((bi * NHEAD + hh) * DHEAD + d)) * T_SEQ + t2b]) = o;
                } else {
                    #pragma unroll
                    for (int r = 0; r < 4; r++) {
                        float v = acc[i][j][r] + bias;
                        float vp = __shfl_xor(v, 1);    // RoPE partner (col^1)
                        int t2 = t2b + r;
                        size_t ci = (size_t)t2 * 32 + (d >> 1);   // broadcast slice (b=0,h=0)
                        float c = cosp[ci], sn2 = sinp[ci];
                        float o = (d & 1) ? (vp * sn2 + v * c) : (v * c - vp * sn2);
                        if (which == 0) o *= 0.18033688f;         // 1/sqrt(DH) * log2(e)
                        outp[((size_t)((bi * NHEAD + hh) * T_SEQ + t2)) * DHEAD + d] = f2bf(o);
                    }
                }
            } else {
                #pragma unroll
                for (int r = 0; r < 4; r++)
                    epi_elem<EPI>(acc[i][j][r], mb + r, n, N, outv, b0, resid);
            }
        }
    }
}

// ---------------- flash attention (MFMA), fixed-max softmax ----------------
__device__ __forceinline__ void attn_step(
    bool diag, int wave, int lm, int ko,
    short8 aq0, short8 aq1,
    const u16 (*sK)[72], const u16 (*sV)[72], u16 (*sPw)[72],
    f32x4* oacc, float* lr)
{
    f32x4 sacc[4];
    #pragma unroll
    for (int j = 0; j < 4; j++) {
        short8 bk0 = *(const short8*)(&sK[j * 16 + lm][ko * 8]);
        short8 bk1 = *(const short8*)(&sK[j * 16 + lm][32 + ko * 8]);
        f32x4 z = (f32x4){0.f, 0.f, 0.f, 0.f};
        z = __builtin_amdgcn_mfma_f32_16x16x32_bf16(aq0, bk0, z, 0, 0, 0);
        z = __builtin_amdgcn_mfma_f32_16x16x32_bf16(aq1, bk1, z, 0, 0, 0);
        sacc[j] = z;
    }
    if (diag) {
        #pragma unroll
        for (int j = 0; j < 4; j++)
            #pragma unroll
            for (int r = 0; r < 4; r++)
                if (j * 16 + lm > wave * 16 + ko * 4 + r) sacc[j][r] = -1e30f;
    }

    u16 pb[4][4];
    #pragma unroll
    for (int j = 0; j < 4; j++)
        #pragma unroll
        for (int r = 0; r < 4; r++) {
            float p = __builtin_amdgcn_exp2f(sacc[j][r]);
            lr[r] += p;
            pb[j][r] = f2bf(p);
        }

    #pragma unroll
    for (int j = 0; j < 4; j++)
        #pragma unroll
        for (int r = 0; r < 4; r++) sPw[ko * 4 + r][j * 16 + lm] = pb[j][r];

    #pragma unroll
    for (int ks = 0; ks < 2; ks++) {
        short8 ap = *(const short8*)(&sPw[lm][ks * 32 + ko * 8]);
        #pragma unroll
        for (int j = 0; j < 4; j++) {
            short8 bv = *(const short8*)(&sV[j * 16 + lm][ks * 32 + ko * 8]);
            oacc[j] = __builtin_amdgcn_mfma_f32_16x16x32_bf16(ap, bv, oacc[j], 0, 0, 0);
        }
    }
}

__global__ __launch_bounds__(256) void fattn_k(const u16* __restrict__ Q,
                                               const u16* __restrict__ K,
                                               const u16* __restrict__ Vt,
                                               u16* __restrict__ out)
{
    __shared__ u16 sQP[4][16][72];
    __shared__ u16 sK[2][64][72];
    __shared__ u16 sV[2][64][72];
    int tid = threadIdx.x;
    int qtA = blockIdx.x;
    int qtB = 31 - qtA;
    int bh = blockIdx.y;
    int wave = tid >> 6, lane = tid & 63, lm = lane & 15, ko = lane >> 4;
    int bi = bh >> 4, hh = bh & 15;

    const u16* Kb = K  + (size_t)bh * T_SEQ * DHEAD;
    const u16* Vb = Vt + (size_t)bh * DHEAD * T_SEQ;
    u16* sQf = &sQP[0][0][0];
    int srow = tid >> 2, scol = (tid & 3) * 16;

    short8 aqA0, aqA1, aqB0, aqB1;
    {
        const u16* QbA = Q + ((size_t)bh * T_SEQ + qtA * 64) * DHEAD + (size_t)srow * DHEAD + scol;
        *(u16x8*)(&sQf[srow * 72 + scol])     = *(const u16x8*)QbA;
        *(u16x8*)(&sQf[srow * 72 + scol + 8]) = *(const u16x8*)(QbA + 8);
        __syncthreads();
        aqA0 = *(const short8*)(&sQf[(wave * 16 + lm) * 72 + ko * 8]);
        aqA1 = *(const short8*)(&sQf[(wave * 16 + lm) * 72 + 32 + ko * 8]);
        __syncthreads();
        const u16* QbB = Q + ((size_t)bh * T_SEQ + qtB * 64) * DHEAD + (size_t)srow * DHEAD + scol;
        *(u16x8*)(&sQf[srow * 72 + scol])     = *(const u16x8*)QbB;
        *(u16x8*)(&sQf[srow * 72 + scol + 8]) = *(const u16x8*)(QbB + 8);
        __syncthreads();
        aqB0 = *(const short8*)(&sQf[(wave * 16 + lm) * 72 + ko * 8]);
        aqB1 = *(const short8*)(&sQf[(wave * 16 + lm) * 72 + 32 + ko * 8]);
    }

    f32x4 oA[4], oB[4];
    float lA[4], lB[4];
    #pragma unroll
    for (int j = 0; j < 4; j++) { oA[j] = (f32x4){0,0,0,0}; oB[j] = (f32x4){0,0,0,0}; }
    #pragma unroll
    for (int r = 0; r < 4; r++) { lA[r] = 0.f; lB[r] = 0.f; }

    int nA = qtA + 1, n = nA + qtB + 1;

    u16x8 pk0, pk1, pv0, pv1;
    {
        const u16* kp = Kb + (size_t)srow * DHEAD + scol;
        pk0 = *(const u16x8*)kp; pk1 = *(const u16x8*)(kp + 8);
        const u16* vp = Vb + (size_t)srow * T_SEQ + scol;
        pv0 = *(const u16x8*)vp; pv1 = *(const u16x8*)(vp + 8);
    }

    for (int i = 0; i < n; i++) {
        bool isA = i < nA;
        int kt = isA ? i : i - nA;
        int buf = i & 1;

        *(u16x8*)(&sK[buf][srow][scol])     = pk0;
        *(u16x8*)(&sK[buf][srow][scol + 8]) = pk1;
        *(u16x8*)(&sV[buf][srow][scol])     = pv0;
        *(u16x8*)(&sV[buf][srow][scol + 8]) = pv1;

        if (i + 1 < n) {
            int kt2 = (i + 1 < nA) ? i + 1 : i + 1 - nA;
            const u16* kp = Kb + ((size_t)(kt2 * 64 + srow)) * DHEAD + scol;
            pk0 = *(const u16x8*)kp; pk1 = *(const u16x8*)(kp + 8);
            const u16* vp = Vb + (size_t)srow * T_SEQ + kt2 * 64 + scol;
            pv0 = *(const u16x8*)vp; pv1 = *(const u16x8*)(vp + 8);
        }

        __syncthreads();

        if (isA)
            attn_step(kt == qtA, wave, lm, ko, aqA0, aqA1, sK[buf], sV[buf], sQP[wave], oA, lA);
        else
            attn_step(kt == qtB, wave, lm, ko, aqB0, aqB1, sK[buf], sV[buf], sQP[wave], oB, lB);
    }

    #pragma unroll
    for (int o = 1; o < 16; o <<= 1)
        #pragma unroll
        for (int r = 0; r < 4; r++) { lA[r] += __shfl_xor(lA[r], o); lB[r] += __shfl_xor(lB[r], o); }
    #pragma unroll
    for (int r = 0; r < 4; r++) { lA[r] = 1.f / lA[r]; lB[r] = 1.f / lB[r]; }
    int qrowA = qtA * 64 + wave * 16, qrowB = qtB * 64 + wave * 16;
    #pragma unroll
    for (int j = 0; j < 4; j++)
        #pragma unroll
        for (int r = 0; r < 4; r++) {
            out[((size_t)(bi * T_SEQ) + qrowA + ko * 4 + r) * DMODEL + hh * DHEAD + j * 16 + lm]
                = f2bf(oA[j][r] * lA[r]);
            out[((size_t)(bi * T_SEQ) + qrowB + ko * 4 + r) * DMODEL + hh * DHEAD + j * 16 + lm]
                = f2bf(oB[j][r] * lB[r]);
        }
}

// ---------------- host launch ----------------
extern "C" void kernel_launch(void* const* d_in, const int* in_sizes, int n_in,
                              void* d_out, int out_size, void* d_ws, size_t ws_size,
                              hipStream_t stream)
{
    (void)in_sizes; (void)n_in; (void)out_size; (void)ws_size;
    const float* x    = (const float*)d_in[0];
    const float* cosp = (const float*)d_in[1];
    const float* sinp = (const float*)d_in[2];
    const float* Wq  = (const float*)d_in[4];
    const float* bq  = (const float*)d_in[5];
    const float* Wk  = (const float*)d_in[6];
    const float* bk  = (const float*)d_in[7];
    const float* Wv  = (const float*)d_in[8];
    const float* bv  = (const float*)d_in[9];
    const float* Wo  = (const float*)d_in[10];
    const float* bo  = (const float*)d_in[11];
    const float* g1  = (const float*)d_in[12];
    const float* b1n = (const float*)d_in[13];
    const float* g2  = (const float*)d_in[14];
    const float* b2n = (const float*)d_in[15];
    const float* W1  = (const float*)d_in[16];
    const float* bf1 = (const float*)d_in[17];
    const float* W2  = (const float*)d_in[18];
    const float* bf2 = (const float*)d_in[19];

    char* ws = (char*)d_ws;
    const size_t MB = 1024 * 1024;
    u16*   qkvT  = (u16*)(ws + 0);        // Wq^T,Wk^T,Wv^T bf16: (3072,1024), 6 MB
    u16*   WoT   = (u16*)(ws + 6 * MB);   // 2 MB
    u16*   W1T   = (u16*)(ws + 8 * MB);   // (4096,1024), 8 MB
    u16*   W2T   = (u16*)(ws + 16 * MB);  // (1024,4096), 8 MB
    u16*   h     = (u16*)(ws + 24 * MB);  // LN output bf16 (reused as h2), 8 MB
    u16*   qkvh  = (u16*)(ws + 32 * MB);  // Q,K in (B,H,T,DH); V in (B,H,DH,T), 3x8 MB
    u16*   attnC = (u16*)(ws + 56 * MB);  // attention out bf16 (B,T,D), 8 MB
    float* x2    = (float*)(ws + 64 * MB);// f32 residual stream, 16 MB
    u16*   ffnh  = (u16*)(ws + 80 * MB);  // bf16 (4096,4096), 32 MB

    trall_k<<<dim3(16, 16, 12), 256, 0, stream>>>(
        Wq, Wk, Wv, Wo, W1, W2,
        qkvT, qkvT + 1 * MB, qkvT + 2 * MB, WoT, W1T, W2T);

    ln_k<<<4096, 256, 0, stream>>>(x, g1, b1n, h);
    gemm8_k<EPI_QKV><<<dim3(24, 32), 512, 0, stream>>>(
        h, qkvT, qkvh, 4096, 3072, 1024, 1024, bq, bk, bv, nullptr, cosp, sinp);
    fattn_k<<<dim3(16, 32), 256, 0, stream>>>(qkvh, qkvh + HBUF, qkvh + 2 * HBUF, attnC);
    gemm8_k<EPI_RESF><<<dim3(8, 32), 512, 0, stream>>>(
        attnC, WoT, x2, 4096, 1024, 1024, 1024, bo, nullptr, nullptr, x, nullptr, nullptr);
    ln_k<<<4096, 256, 0, stream>>>(x2, g2, b2n, h);
    gemm8_k<EPI_GELU><<<dim3(32, 32), 512, 0, stream>>>(
        h, W1T, ffnh, 4096, 4096, 1024, 1024, bf1, nullptr, nullptr, nullptr, nullptr, nullptr);
    gemm8_k<EPI_RES2><<<dim3(8, 32), 512, 0, stream>>>(
        ffnh, W2T, (float*)d_out, 4096, 1024, 4096, 4096, bf2, nullptr, nullptr, x2, nullptr, nullptr);
}